// Round 8
// baseline (166.852 us; speedup 1.0000x reference)
//
#include <hip/hip_runtime.h>
#include <hip/hip_bf16.h>

#define B_   8
#define S_   1024
#define HID_ 1024
#define H_   16
#define D_   64

typedef __hip_bfloat16 bf16;
typedef __attribute__((ext_vector_type(8))) short s16x8;   // MFMA A/B frag (8 bf16)
typedef __attribute__((ext_vector_type(4))) float f32x4;   // MFMA C/D frag

// Fragment-order workspace layouts (indices in bf16 elements):
//  Qf/Kf: per bh (128 KiB): 64 row-tiles of 16 rows; per tile 1024 elems =
//         [half(2)][lane(64)][8]; lane (quad,c) holds row c, features
//         half*32+quad*8..+8  (exactly the attn A/B frag).
//  Vf:    per bh: 16 key-tiles; per tile 4096 = [et(4)][p(2)][lane(64)][8];
//         lane slot = V[key p*32+quad*4+j][feat et*16+c] (j=0..3), key+16
//         for j=4..7 — the paired-chunk PV B-frag.
//  Wf:    per (m,h): 4096 = [et(4)][half(2)][lane(64)][8].
#define QK_BH 65536
#define V_BH  65536

// f32 -> bf16 bits, round-half-up (add + shift; 2 VALU)
__device__ __forceinline__ short f2b(float f) {
    union { float f; unsigned u; } a; a.f = f;
    return (short)((a.u + 0x8000u) >> 16);
}
// load 8 consecutive f32 (32B, aligned) -> bf16 half-fragment
__device__ __forceinline__ s16x8 cvt8(const float* p) {
    const float4* q = (const float4*)p;
    float4 u = q[0], v = q[1];
    s16x8 r;
    r[0] = f2b(u.x); r[1] = f2b(u.y); r[2] = f2b(u.z); r[3] = f2b(u.w);
    r[4] = f2b(v.x); r[5] = f2b(v.y); r[6] = f2b(v.z); r[7] = f2b(v.w);
    return r;
}
__device__ __forceinline__ s16x8 load8bf(const bf16* p) {
    return *(const s16x8*)p;   // 16B load; callers guarantee alignment
}

// packed f32x2 -> bf16x2 (1 VALU for 2 elems, writes the packed dword)
__device__ __forceinline__ unsigned cvtpk_bf16(float lo, float hi) {
    unsigned r;
    asm("v_cvt_pk_bf16_f32 %0, %1, %2" : "=v"(r) : "v"(lo), "v"(hi));
    return r;
}

// ---------------------------------------------------------------------------
// Kernel 0: one-shot W f32 -> bf16 in FRAGMENT ORDER.
// ---------------------------------------------------------------------------
__global__ __launch_bounds__(256) void cvt_w(
    const float* __restrict__ Wq, const float* __restrict__ Wk,
    const float* __restrict__ Wv, bf16* __restrict__ Wf)
{
    const float* srcs[3] = {Wq, Wk, Wv};
    const float* src = srcs[blockIdx.y];
    bf16* dst = Wf + (size_t)blockIdx.y * (H_ * D_ * D_);
    const int i = blockIdx.x * 256 + threadIdx.x;   // 0..8191
    const int h = i >> 9;            // 512 threads per head
    const int r = i & 511;
    const int et = r >> 7, half = (r >> 6) & 1, lane = r & 63;
    const int quad = lane >> 4, c = lane & 15;
    const float* s = src + h * 4096 + (et * 16 + c) * 64 + half * 32 + quad * 8;
    bf16* d = dst + h * 4096 + et * 1024 + half * 512 + lane * 8;
    *(s16x8*)d = cvt8(s);
}

// ---------------------------------------------------------------------------
// Kernel 1: QKV projection, FRAGMENT-ORDER outputs, 64-row blocks.
// grid 2048 (bh = id&127, sc = id>>7 over 16 chunks of 64 rows), block 256.
// Each wave owns 16 rows (one row-tile / one quarter of the V key-tile).
// ---------------------------------------------------------------------------
__global__ __launch_bounds__(256) void qkv_proj(
    const float* __restrict__ x, const bf16* __restrict__ Wf,
    const float* __restrict__ bq, const float* __restrict__ bk,
    const float* __restrict__ bv,
    bf16* __restrict__ Qf, bf16* __restrict__ Kf, bf16* __restrict__ Vf)
{
    __shared__ __align__(16) bf16 xs[64][72];   // 9 KiB, stride-72 padding

    const int id = blockIdx.x;
    const int bh_i = id & 127, sc = id >> 7;    // sc: 64-row chunk 0..15
    const int b = bh_i >> 4, h = bh_i & 15;
    const int t = threadIdx.x;
    const int wave = t >> 6, lane = t & 63;
    const int quad = lane >> 4, c = lane & 15;
    const size_t bh = (size_t)bh_i;

    // ---- stage x[rows sc*64..+64)[h*64..+64) -> bf16 LDS, coalesced ----
    {
        const float* xg = x + ((size_t)b * S_ + sc * 64) * HID_ + h * D_;
#pragma unroll
        for (int i = 0; i < 4; ++i) {
            const int j = i * 256 + t;          // 1024 float4 segments
            const int row = j >> 4, seg = j & 15;
            float4 v = *(const float4*)(xg + (size_t)row * HID_ + seg * 4);
            short4 pk;
            pk.x = f2b(v.x); pk.y = f2b(v.y); pk.z = f2b(v.z); pk.w = f2b(v.w);
            *(short4*)&xs[row][seg * 4] = pk;
        }
    }
    __syncthreads();

    // X frag for this wave's row-tile (rows wave*16 + c)
    s16x8 xa0 = *(const s16x8*)&xs[wave * 16 + c][quad * 8];
    s16x8 xa1 = *(const s16x8*)&xs[wave * 16 + c][32 + quad * 8];

    const float* bs[3] = {bq, bk, bv};

#pragma unroll
    for (int m = 0; m < 3; ++m) {
        const bf16*  Wm   = Wf + ((size_t)m * H_ + h) * 4096;
        const float* bias = bs[m] + h * D_;
#pragma unroll
        for (int et = 0; et < 4; ++et) {
            s16x8 wf0 = load8bf(Wm + et * 1024 + lane * 8);         // half 0
            s16x8 wf1 = load8bf(Wm + et * 1024 + 512 + lane * 8);   // half 1
            if (m < 2) {
                // D[e][s] = W·X^T : lane holds feats f = et*16+quad*4+r of
                // row (sc*4+wave)*16 + c.
                const int hp = et >> 1;
                const int qp = (2 * et + (quad >> 1)) & 3;
                const float4 bb = *(const float4*)&bias[et * 16 + quad * 4];
                f32x4 acc = {0.f, 0.f, 0.f, 0.f};
                acc = __builtin_amdgcn_mfma_f32_16x16x32_bf16(wf0, xa0, acc, 0, 0, 0);
                acc = __builtin_amdgcn_mfma_f32_16x16x32_bf16(wf1, xa1, acc, 0, 0, 0);
                const int ts = sc * 4 + wave;   // row-tile index
                bf16* dst = (m == 0 ? Qf : Kf) + bh * QK_BH + ts * 1024 +
                            hp * 512 + (qp * 16 + c) * 8 + (quad & 1) * 4;
                short4 pk;
                pk.x = f2b(acc[0] + bb.x);
                pk.y = f2b(acc[1] + bb.y);
                pk.z = f2b(acc[2] + bb.z);
                pk.w = f2b(acc[3] + bb.w);
                *(short4*)dst = pk;
            } else {
                // D[s][e] = X·W^T : lane holds keys wave*16+quad*4+r of
                // feature et*16+c. Key-tile = sc; p = wave>>1, hi = wave&1.
                const float bbv = bias[et * 16 + c];
                f32x4 acc = {0.f, 0.f, 0.f, 0.f};
                acc = __builtin_amdgcn_mfma_f32_16x16x32_bf16(xa0, wf0, acc, 0, 0, 0);
                acc = __builtin_amdgcn_mfma_f32_16x16x32_bf16(xa1, wf1, acc, 0, 0, 0);
                bf16* dst = Vf + bh * V_BH + sc * 4096 + et * 1024 +
                            (wave >> 1) * 512 + (quad * 16 + c) * 8 + (wave & 1) * 4;
                short4 pk;
                pk.x = f2b(acc[0] + bbv);
                pk.y = f2b(acc[1] + bbv);
                pk.z = f2b(acc[2] + bbv);
                pk.w = f2b(acc[3] + bbv);
                *(short4*)dst = pk;
            }
        }
    }
}

// ---------------------------------------------------------------------------
// Kernel 2: MFMA flash attention.  v9: v8's shape with REGISTER-STAGED LDS.
// Bisect over v2..v8 isolated the failure predictor to {2-tile/wave} x
// {global_load_lds}: the DMA's LDS-write side is invisible to the compiler
// (m104/m108), and the short 2-tile body evidently lets the scheduler break
// the publish protocol.  v9 eliminates the invisible dependency: staging is
// global_load_dwordx4 -> VGPR -> ds_write_b128 (T14 split: loads issued at
// loop top, hidden under compute; ds_write after compute into the buffer
// consumed last iteration; one barrier publishes).  Every dependency is
// now native, compiler-visible LDS dataflow.
// 512-thread / 8-wave blocks, grid 512 (bh = id&127, qc = id>>7, 256 rows
// per block), 2 row-tiles/wave -> 4096 waves = 4 waves/SIMD, staging
// amortized over 8 waves (FETCH stays ~29 MB, unlike v7's 41.7).
// LDS 34.8 KiB (os unioned; epilogue starts after final barrier).
// ---------------------------------------------------------------------------
__global__ __launch_bounds__(512, 2) void attn(
    const bf16* __restrict__ Qf, const bf16* __restrict__ Kf,
    const bf16* __restrict__ Vf, float* __restrict__ out)
{
    __shared__ __align__(16) union {
        bf16  kv[2][8192];        // [buf][ K: 4096 elems | V: 4096 elems ]
        float os[8][16][68];      // epilogue staging (after last barrier)
    } sm;

    const int id = blockIdx.x;
    const int bh_i = id & 127, qc = id >> 7;        // qc 0..3, 256 rows each
    const int b = bh_i >> 4, h = bh_i & 15;
    const int wave = threadIdx.x >> 6, lane = threadIdx.x & 63;   // wave 0..7
    const int quad = lane >> 4, c = lane & 15;
    const int ts0 = qc * 16 + wave * 2;             // first of 2 row-tiles
    const size_t bh = (size_t)bh_i;

    // Q fragments for 2 row-tiles (B-operand of swapped QK)
    s16x8 aq[2][2];
#pragma unroll
    for (int mt = 0; mt < 2; ++mt) {
        const bf16* Qb = Qf + bh * QK_BH + (ts0 + mt) * 1024 + lane * 8;
        aq[mt][0] = load8bf(Qb);
        aq[mt][1] = load8bf(Qb + 512);
    }

    const f32x4 zero4 = {0.f, 0.f, 0.f, 0.f};
    f32x4 o[2][4];
    f32x4 ld4[2];                 // denominator accumulators (ones-MFMA)
#pragma unroll
    for (int mt = 0; mt < 2; ++mt) {
        ld4[mt] = zero4;
#pragma unroll
        for (int et = 0; et < 4; ++et) o[mt][et] = zero4;
    }

    s16x8 ones;                   // bf16 1.0 B-fragment
#pragma unroll
    for (int j = 0; j < 8; ++j) ones[j] = (short)0x3F80;

    const float CEXP = 0.18033688011112042f;           // (1/sqrt(64))*log2(e)
    const float NM0  = -16.0f * 0.18033688011112042f;  // fixed shift m0=16

    const bf16* Kg = Kf + bh * QK_BH;   // + kt*4096 elems per k-tile (8 KB)
    const bf16* Vg = Vf + bh * V_BH;    // + kt*4096 elems per k-tile (8 KB)

    // Register-staged tile transfer: wave w owns chunks w*2, w*2+1 of the
    // 16 x 1 KB chunk grid (waves 0-3 -> K, waves 4-7 -> V).
    uint4 stg[2];
    auto STAGE_LOAD = [&](int kt) {         // global -> VGPR (issue early)
#pragma unroll
        for (int i = 0; i < 2; ++i) {
            const int ch = wave * 2 + i;                      // 0..15
            const bf16* src = (ch < 8
                ? Kg + (size_t)kt * 4096 + ch * 512
                : Vg + (size_t)kt * 4096 + (ch - 8) * 512) + lane * 8;
            stg[i] = *(const uint4*)src;
        }
    };
    auto STAGE_WRITE = [&](int bi) {        // VGPR -> LDS (after compute)
#pragma unroll
        for (int i = 0; i < 2; ++i) {
            const int ch = wave * 2 + i;
            *(uint4*)&sm.kv[bi][ch * 512 + lane * 8] = stg[i];
        }
    };

    STAGE_LOAD(0);
    STAGE_WRITE(0);
    __syncthreads();              // buf0 published

    int cur = 0;
#pragma unroll 1
    for (int kt = 0; kt < S_ / 64; ++kt) {
        // issue next tile's global loads now; they land in VGPRs under the
        // compute below and are written to LDS just before the barrier
        if (kt < S_ / 64 - 1) STAGE_LOAD(kt + 1);

        const bf16* kb = &sm.kv[cur][0];
        const bf16* vb = &sm.kv[cur][4096];

        // ---- tile fragments from LDS (16 linear ds_read_b128 / lane) ----
        s16x8 ka[4], kb2[4];
#pragma unroll
        for (int ct = 0; ct < 4; ++ct) {
            ka[ct]  = load8bf(kb + ct * 1024 + lane * 8);
            kb2[ct] = load8bf(kb + ct * 1024 + 512 + lane * 8);
        }
        s16x8 vf4[4][2];
#pragma unroll
        for (int et = 0; et < 4; ++et)
#pragma unroll
            for (int p = 0; p < 2; ++p)
                vf4[et][p] = load8bf(vb + et * 1024 + p * 512 + lane * 8);

        // ---- per row-tile: QK^T -> softmax -> PV (P stays in registers) --
#pragma unroll
        for (int mt = 0; mt < 2; ++mt) {
            f32x4 s4[4];
#pragma unroll
            for (int ct = 0; ct < 4; ++ct) {
                f32x4 acc = zero4;
                acc = __builtin_amdgcn_mfma_f32_16x16x32_bf16(ka[ct],  aq[mt][0], acc, 0, 0, 0);
                acc = __builtin_amdgcn_mfma_f32_16x16x32_bf16(kb2[ct], aq[mt][1], acc, 0, 0, 0);
                s4[ct] = acc;
            }
            s16x8 pz[2];
#pragma unroll
            for (int p = 0; p < 2; ++p) {
                float pa[4], pb[4];
#pragma unroll
                for (int j = 0; j < 4; ++j) {
                    pa[j] = __builtin_amdgcn_exp2f(fmaf(s4[2 * p][j],     CEXP, NM0));
                    pb[j] = __builtin_amdgcn_exp2f(fmaf(s4[2 * p + 1][j], CEXP, NM0));
                }
                union { unsigned u[4]; s16x8 v; } z;
                z.u[0] = cvtpk_bf16(pa[0], pa[1]);
                z.u[1] = cvtpk_bf16(pa[2], pa[3]);
                z.u[2] = cvtpk_bf16(pb[0], pb[1]);
                z.u[3] = cvtpk_bf16(pb[2], pb[3]);
                pz[p] = z.v;
            }
            // denominator: row-sum of bf16 P via ones-column MFMA
            ld4[mt] = __builtin_amdgcn_mfma_f32_16x16x32_bf16(pz[0], ones, ld4[mt], 0, 0, 0);
            ld4[mt] = __builtin_amdgcn_mfma_f32_16x16x32_bf16(pz[1], ones, ld4[mt], 0, 0, 0);
#pragma unroll
            for (int et = 0; et < 4; ++et) {
                o[mt][et] = __builtin_amdgcn_mfma_f32_16x16x32_bf16(pz[0], vf4[et][0], o[mt][et], 0, 0, 0);
                o[mt][et] = __builtin_amdgcn_mfma_f32_16x16x32_bf16(pz[1], vf4[et][1], o[mt][et], 0, 0, 0);
            }
        }

        // write next tile into buf[cur^1] (fully consumed in iteration
        // kt-1; the end-of-(kt-1) barrier ordered those reads before us)
        if (kt < S_ / 64 - 1) STAGE_WRITE(cur ^ 1);
        __syncthreads();          // publish buf[cur^1]; close reads of cur
        cur ^= 1;
    }

    // ---- epilogue per row-tile: ld4[mt][r] already holds the full row
    //      denom (replicated across the 16 lanes of the row group -> no
    //      shuffles), normalize, LDS transpose, contiguous float4 stores.
    //      sm.kv is dead after the final barrier above; os aliases it. ----
#pragma unroll
    for (int mt = 0; mt < 2; ++mt) {
        float inv[4];
#pragma unroll
        for (int r = 0; r < 4; ++r) inv[r] = 1.0f / ld4[mt][r];
#pragma unroll
        for (int et = 0; et < 4; ++et)
#pragma unroll
            for (int r = 0; r < 4; ++r)
                sm.os[wave][quad * 4 + r][et * 16 + c] = o[mt][et][r] * inv[r];
        float* orow = out + ((size_t)b * S_ + (ts0 + mt) * 16 + c) * HID_ + h * D_;
#pragma unroll
        for (int j = 0; j < 4; ++j) {
            float4 v = *(const float4*)&sm.os[wave][c][(quad + j * 4) * 4];
            *(float4*)(orow + (quad + j * 4) * 4) = v;
        }
    }
}

// ---------------------------------------------------------------------------
extern "C" void kernel_launch(void* const* d_in, const int* in_sizes, int n_in,
                              void* d_out, int out_size, void* d_ws, size_t ws_size,
                              hipStream_t stream) {
    (void)in_sizes; (void)n_in; (void)out_size; (void)ws_size;
    const float* x  = (const float*)d_in[0];
    const float* Wq = (const float*)d_in[1];
    const float* bq = (const float*)d_in[2];
    const float* Wk = (const float*)d_in[3];
    const float* bk = (const float*)d_in[4];
    const float* Wv = (const float*)d_in[5];
    const float* bv = (const float*)d_in[6];
    float* outp = (float*)d_out;   // reference output dtype is float32

    bf16* Qfw = (bf16*)d_ws;                       // 128 bh * 64K elems
    bf16* Kfw = Qfw + (size_t)128 * QK_BH;
    bf16* Vfw = Kfw + (size_t)128 * QK_BH;
    bf16* Wfw = Vfw + (size_t)128 * V_BH;          // + 384 KiB fragment-order W

    cvt_w<<<dim3(32, 3), 256, 0, stream>>>(Wq, Wk, Wv, Wfw);
    qkv_proj<<<dim3(2048), 256, 0, stream>>>(x, Wfw, bq, bk, bv, Qfw, Kfw, Vfw);
    attn<<<dim3(512), 512, 0, stream>>>(Qfw, Kfw, Vfw, outp);
}

// Round 11
// 141.093 us; speedup vs baseline: 1.1826x; 1.1826x over previous
//
#include <hip/hip_runtime.h>
#include <hip/hip_bf16.h>

#define B_   8
#define S_   1024
#define HID_ 1024
#define H_   16
#define D_   64

typedef __hip_bfloat16 bf16;
typedef __attribute__((ext_vector_type(8))) short s16x8;   // MFMA A/B frag (8 bf16)
typedef __attribute__((ext_vector_type(4))) float f32x4;   // MFMA C/D frag

// Fragment-order workspace layouts (indices in bf16 elements):
//  Qf/Kf: per bh (128 KiB): 64 row-tiles of 16 rows; per tile 1024 elems =
//         [half(2)][lane(64)][8]; lane (quad,c) holds row c, features
//         half*32+quad*8..+8  (exactly the attn A/B frag).
//  Vf:    per bh: 16 key-tiles; per tile 4096 = [et(4)][p(2)][lane(64)][8];
//         lane slot = V[key p*32+quad*4+j][feat et*16+c] (j=0..3), key+16
//         for j=4..7 — the paired-chunk PV B-frag.
//  Wf:    per (m,h): 4096 = [et(4)][half(2)][lane(64)][8].
#define QK_BH 65536
#define V_BH  65536

// f32 -> bf16 bits, round-half-up (add + shift; 2 VALU)
__device__ __forceinline__ short f2b(float f) {
    union { float f; unsigned u; } a; a.f = f;
    return (short)((a.u + 0x8000u) >> 16);
}
// load 8 consecutive f32 (32B, aligned) -> bf16 half-fragment
__device__ __forceinline__ s16x8 cvt8(const float* p) {
    const float4* q = (const float4*)p;
    float4 u = q[0], v = q[1];
    s16x8 r;
    r[0] = f2b(u.x); r[1] = f2b(u.y); r[2] = f2b(u.z); r[3] = f2b(u.w);
    r[4] = f2b(v.x); r[5] = f2b(v.y); r[6] = f2b(v.z); r[7] = f2b(v.w);
    return r;
}
__device__ __forceinline__ s16x8 load8bf(const bf16* p) {
    return *(const s16x8*)p;   // 16B load; callers guarantee alignment
}

// packed f32x2 -> bf16x2 (1 VALU for 2 elems, writes the packed dword)
__device__ __forceinline__ unsigned cvtpk_bf16(float lo, float hi) {
    unsigned r;
    asm("v_cvt_pk_bf16_f32 %0, %1, %2" : "=v"(r) : "v"(lo), "v"(hi));
    return r;
}

// async global->LDS, 16B per lane; LDS dest = wave-uniform base + lane*16
typedef __attribute__((address_space(1))) const void gvoid_t;
typedef __attribute__((address_space(3))) void lvoid_t;
__device__ __forceinline__ void gload_lds16(const bf16* g, bf16* l) {
    __builtin_amdgcn_global_load_lds((gvoid_t*)g, (lvoid_t*)l, 16, 0, 0);
}

// ---------------------------------------------------------------------------
// Kernel 0: one-shot W f32 -> bf16 in FRAGMENT ORDER.
// ---------------------------------------------------------------------------
__global__ __launch_bounds__(256) void cvt_w(
    const float* __restrict__ Wq, const float* __restrict__ Wk,
    const float* __restrict__ Wv, bf16* __restrict__ Wf)
{
    const float* srcs[3] = {Wq, Wk, Wv};
    const float* src = srcs[blockIdx.y];
    bf16* dst = Wf + (size_t)blockIdx.y * (H_ * D_ * D_);
    const int i = blockIdx.x * 256 + threadIdx.x;   // 0..8191
    const int h = i >> 9;            // 512 threads per head
    const int r = i & 511;
    const int et = r >> 7, half = (r >> 6) & 1, lane = r & 63;
    const int quad = lane >> 4, c = lane & 15;
    const float* s = src + h * 4096 + (et * 16 + c) * 64 + half * 32 + quad * 8;
    bf16* d = dst + h * 4096 + et * 1024 + half * 512 + lane * 8;
    *(s16x8*)d = cvt8(s);
}

// ---------------------------------------------------------------------------
// Kernel 1: QKV projection, FRAGMENT-ORDER outputs, 64-row blocks.
// grid 2048 (bh = id&127, sc = id>>7 over 16 chunks of 64 rows), block 256.
// Each wave owns 16 rows (one row-tile / one quarter of the V key-tile).
// v11 change: the m-loop is SERIALIZED (#pragma unroll 1).  Fully unrolled
// m x et held ~24 W-fragments (96 VGPR) + accs + staging in flight —
// suspected >256-VGPR spill-to-scratch regime (this kernel has been ~80 µs
// vs a 13 µs roofline since R0, never touched).  Rolled: each phase needs
// only 8 W-frag VGPRs + 4 accs.  Arithmetic/addressing byte-identical.
// ---------------------------------------------------------------------------
__global__ __launch_bounds__(256) void qkv_proj(
    const float* __restrict__ x, const bf16* __restrict__ Wf,
    const float* __restrict__ bq, const float* __restrict__ bk,
    const float* __restrict__ bv,
    bf16* __restrict__ Qf, bf16* __restrict__ Kf, bf16* __restrict__ Vf)
{
    __shared__ __align__(16) bf16 xs[64][72];   // 9 KiB, stride-72 padding

    const int id = blockIdx.x;
    const int bh_i = id & 127, sc = id >> 7;    // sc: 64-row chunk 0..15
    const int b = bh_i >> 4, h = bh_i & 15;
    const int t = threadIdx.x;
    const int wave = t >> 6, lane = t & 63;
    const int quad = lane >> 4, c = lane & 15;
    const size_t bh = (size_t)bh_i;

    // ---- stage x[rows sc*64..+64)[h*64..+64) -> bf16 LDS, coalesced ----
    {
        const float* xg = x + ((size_t)b * S_ + sc * 64) * HID_ + h * D_;
#pragma unroll
        for (int i = 0; i < 4; ++i) {
            const int j = i * 256 + t;          // 1024 float4 segments
            const int row = j >> 4, seg = j & 15;
            float4 v = *(const float4*)(xg + (size_t)row * HID_ + seg * 4);
            short4 pk;
            pk.x = f2b(v.x); pk.y = f2b(v.y); pk.z = f2b(v.z); pk.w = f2b(v.w);
            *(short4*)&xs[row][seg * 4] = pk;
        }
    }
    __syncthreads();

    // X frag for this wave's row-tile (rows wave*16 + c)
    s16x8 xa0 = *(const s16x8*)&xs[wave * 16 + c][quad * 8];
    s16x8 xa1 = *(const s16x8*)&xs[wave * 16 + c][32 + quad * 8];

    const float* bs[3] = {bq, bk, bv};

#pragma unroll 1
    for (int m = 0; m < 3; ++m) {
        const bf16*  Wm   = Wf + ((size_t)m * H_ + h) * 4096;
        const float* bias = bs[m] + h * D_;
#pragma unroll
        for (int et = 0; et < 4; ++et) {
            s16x8 wf0 = load8bf(Wm + et * 1024 + lane * 8);         // half 0
            s16x8 wf1 = load8bf(Wm + et * 1024 + 512 + lane * 8);   // half 1
            if (m < 2) {
                // D[e][s] = W·X^T : lane holds feats f = et*16+quad*4+r of
                // row (sc*4+wave)*16 + c.
                const int hp = et >> 1;
                const int qp = (2 * et + (quad >> 1)) & 3;
                const float4 bb = *(const float4*)&bias[et * 16 + quad * 4];
                f32x4 acc = {0.f, 0.f, 0.f, 0.f};
                acc = __builtin_amdgcn_mfma_f32_16x16x32_bf16(wf0, xa0, acc, 0, 0, 0);
                acc = __builtin_amdgcn_mfma_f32_16x16x32_bf16(wf1, xa1, acc, 0, 0, 0);
                const int ts = sc * 4 + wave;   // row-tile index
                bf16* dst = (m == 0 ? Qf : Kf) + bh * QK_BH + ts * 1024 +
                            hp * 512 + (qp * 16 + c) * 8 + (quad & 1) * 4;
                short4 pk;
                pk.x = f2b(acc[0] + bb.x);
                pk.y = f2b(acc[1] + bb.y);
                pk.z = f2b(acc[2] + bb.z);
                pk.w = f2b(acc[3] + bb.w);
                *(short4*)dst = pk;
            } else {
                // D[s][e] = X·W^T : lane holds keys wave*16+quad*4+r of
                // feature et*16+c. Key-tile = sc; p = wave>>1, hi = wave&1.
                const float bbv = bias[et * 16 + c];
                f32x4 acc = {0.f, 0.f, 0.f, 0.f};
                acc = __builtin_amdgcn_mfma_f32_16x16x32_bf16(xa0, wf0, acc, 0, 0, 0);
                acc = __builtin_amdgcn_mfma_f32_16x16x32_bf16(xa1, wf1, acc, 0, 0, 0);
                bf16* dst = Vf + bh * V_BH + sc * 4096 + et * 1024 +
                            (wave >> 1) * 512 + (quad * 16 + c) * 8 + (wave & 1) * 4;
                short4 pk;
                pk.x = f2b(acc[0] + bbv);
                pk.y = f2b(acc[1] + bbv);
                pk.z = f2b(acc[2] + bbv);
                pk.w = f2b(acc[3] + bbv);
                *(short4*)dst = pk;
            }
        }
    }
}

// ---------------------------------------------------------------------------
// Kernel 2: MFMA flash attention — the PROVEN v2/v6 form, byte-identical
// to R1 (grid 512, 4 row-tiles/wave, 2 blocks/CU, global_load_lds dbuf in
// its only verified shape).  Occupancy arc closed after 6 attempts: every
// restructuring around global_load_lds corrupts (v3,v4,v5,v8,v10); the
// alternatives that pass (reg-staged v9, unstaged v7) are slower.
// ---------------------------------------------------------------------------
__global__ __launch_bounds__(256, 2) void attn(
    const bf16* __restrict__ Qf, const bf16* __restrict__ Kf,
    const bf16* __restrict__ Vf, float* __restrict__ out)
{
    __shared__ __align__(16) union {
        bf16  kv[2][8192];        // [buf][ K: 4096 elems | V: 4096 elems ]
        float os[4][16][68];      // epilogue staging (after last barrier)
    } sm;

    const int id = blockIdx.x;
    const int bh_i = id & 127, qc = id >> 7;        // qc 0..3, 256 rows each
    const int b = bh_i >> 4, h = bh_i & 15;
    const int wave = threadIdx.x >> 6, lane = threadIdx.x & 63;
    const int quad = lane >> 4, c = lane & 15;
    const int ts0 = qc * 16 + wave * 4;             // first of 4 row-tiles
    const size_t bh = (size_t)bh_i;

    // Q fragments for 4 row-tiles (B-operand of swapped QK)
    s16x8 aq[4][2];
#pragma unroll
    for (int mt = 0; mt < 4; ++mt) {
        const bf16* Qb = Qf + bh * QK_BH + (ts0 + mt) * 1024 + lane * 8;
        aq[mt][0] = load8bf(Qb);
        aq[mt][1] = load8bf(Qb + 512);
    }

    const f32x4 zero4 = {0.f, 0.f, 0.f, 0.f};
    f32x4 o[4][4];
    f32x4 ld4[4];                 // denominator accumulators (ones-MFMA)
#pragma unroll
    for (int mt = 0; mt < 4; ++mt) {
        ld4[mt] = zero4;
#pragma unroll
        for (int et = 0; et < 4; ++et) o[mt][et] = zero4;
    }

    s16x8 ones;                   // bf16 1.0 B-fragment
#pragma unroll
    for (int j = 0; j < 8; ++j) ones[j] = (short)0x3F80;

    const float CEXP = 0.18033688011112042f;           // (1/sqrt(64))*log2(e)
    const float NM0  = -16.0f * 0.18033688011112042f;  // fixed shift m0=16

    const bf16* Kg = Kf + bh * QK_BH;   // + kt*4096 elems per k-tile (8 KB)
    const bf16* Vg = Vf + bh * V_BH;    // + kt*4096 elems per k-tile (8 KB)

    // stage one 16 KB k-tile (K 8 KB | V 8 KB) into LDS buffer bi.
    // 16 chunks of 1 KB; wave w issues chunks w*4..w*4+3 (waves 0,1 -> K,
    // waves 2,3 -> V).  LDS dest linear: uniform base + lane*16B.
    auto STAGE = [&](int kt, int bi) {
#pragma unroll
        for (int i = 0; i < 4; ++i) {
            const int ch = wave * 4 + i;                      // 0..15
            const bf16* src = (ch < 8
                ? Kg + (size_t)kt * 4096 + ch * 512
                : Vg + (size_t)kt * 4096 + (ch - 8) * 512) + lane * 8;
            gload_lds16(src, &sm.kv[bi][ch * 512]);
        }
    };

    STAGE(0, 0);
    __syncthreads();              // drains vmcnt -> buf0 ready

    int cur = 0;
#pragma unroll 1
    for (int kt = 0; kt < S_ / 64; ++kt) {
        // prefetch next tile into the other buffer (drained at this
        // iteration's end-of-loop barrier -> hidden under compute below)
        if (kt < S_ / 64 - 1) STAGE(kt + 1, cur ^ 1);

        const bf16* kb = &sm.kv[cur][0];
        const bf16* vb = &sm.kv[cur][4096];

        // ---- tile fragments from LDS (16 linear ds_read_b128 / lane) ----
        s16x8 ka[4], kb2[4];
#pragma unroll
        for (int ct = 0; ct < 4; ++ct) {
            ka[ct]  = load8bf(kb + ct * 1024 + lane * 8);
            kb2[ct] = load8bf(kb + ct * 1024 + 512 + lane * 8);
        }
        s16x8 vf4[4][2];
#pragma unroll
        for (int et = 0; et < 4; ++et)
#pragma unroll
            for (int p = 0; p < 2; ++p)
                vf4[et][p] = load8bf(vb + et * 1024 + p * 512 + lane * 8);

        // ---- per row-tile: QK^T -> softmax -> PV (P stays in registers) --
#pragma unroll
        for (int mt = 0; mt < 4; ++mt) {
            f32x4 s4[4];
#pragma unroll
            for (int ct = 0; ct < 4; ++ct) {
                f32x4 acc = zero4;
                acc = __builtin_amdgcn_mfma_f32_16x16x32_bf16(ka[ct],  aq[mt][0], acc, 0, 0, 0);
                acc = __builtin_amdgcn_mfma_f32_16x16x32_bf16(kb2[ct], aq[mt][1], acc, 0, 0, 0);
                s4[ct] = acc;
            }
            s16x8 pz[2];
#pragma unroll
            for (int p = 0; p < 2; ++p) {
                float pa[4], pb[4];
#pragma unroll
                for (int j = 0; j < 4; ++j) {
                    pa[j] = __builtin_amdgcn_exp2f(fmaf(s4[2 * p][j],     CEXP, NM0));
                    pb[j] = __builtin_amdgcn_exp2f(fmaf(s4[2 * p + 1][j], CEXP, NM0));
                }
                union { unsigned u[4]; s16x8 v; } z;
                z.u[0] = cvtpk_bf16(pa[0], pa[1]);
                z.u[1] = cvtpk_bf16(pa[2], pa[3]);
                z.u[2] = cvtpk_bf16(pb[0], pb[1]);
                z.u[3] = cvtpk_bf16(pb[2], pb[3]);
                pz[p] = z.v;
            }
            // denominator: row-sum of bf16 P via ones-column MFMA
            ld4[mt] = __builtin_amdgcn_mfma_f32_16x16x32_bf16(pz[0], ones, ld4[mt], 0, 0, 0);
            ld4[mt] = __builtin_amdgcn_mfma_f32_16x16x32_bf16(pz[1], ones, ld4[mt], 0, 0, 0);
#pragma unroll
            for (int et = 0; et < 4; ++et) {
                o[mt][et] = __builtin_amdgcn_mfma_f32_16x16x32_bf16(pz[0], vf4[et][0], o[mt][et], 0, 0, 0);
                o[mt][et] = __builtin_amdgcn_mfma_f32_16x16x32_bf16(pz[1], vf4[et][1], o[mt][et], 0, 0, 0);
            }
        }
        __syncthreads();          // all waves done with kv[cur]; prefetch
        cur ^= 1;                 // into kv[cur^1] drained (vmcnt 0)
    }

    // ---- epilogue per row-tile: ld4[mt][r] already holds the full row
    //      denom (replicated across the 16 lanes of the row group -> no
    //      shuffles), normalize, LDS transpose, contiguous float4 stores.
    //      sm.kv is dead after the final barrier above; os aliases it. ----
#pragma unroll
    for (int mt = 0; mt < 4; ++mt) {
        float inv[4];
#pragma unroll
        for (int r = 0; r < 4; ++r) inv[r] = 1.0f / ld4[mt][r];
#pragma unroll
        for (int et = 0; et < 4; ++et)
#pragma unroll
            for (int r = 0; r < 4; ++r)
                sm.os[wave][quad * 4 + r][et * 16 + c] = o[mt][et][r] * inv[r];
        float* orow = out + ((size_t)b * S_ + (ts0 + mt) * 16 + c) * HID_ + h * D_;
#pragma unroll
        for (int j = 0; j < 4; ++j) {
            float4 v = *(const float4*)&sm.os[wave][c][(quad + j * 4) * 4];
            *(float4*)(orow + (quad + j * 4) * 4) = v;
        }
    }
}

// ---------------------------------------------------------------------------
extern "C" void kernel_launch(void* const* d_in, const int* in_sizes, int n_in,
                              void* d_out, int out_size, void* d_ws, size_t ws_size,
                              hipStream_t stream) {
    (void)in_sizes; (void)n_in; (void)out_size; (void)ws_size;
    const float* x  = (const float*)d_in[0];
    const float* Wq = (const float*)d_in[1];
    const float* bq = (const float*)d_in[2];
    const float* Wk = (const float*)d_in[3];
    const float* bk = (const float*)d_in[4];
    const float* Wv = (const float*)d_in[5];
    const float* bv = (const float*)d_in[6];
    float* outp = (float*)d_out;   // reference output dtype is float32

    bf16* Qfw = (bf16*)d_ws;                       // 128 bh * 64K elems
    bf16* Kfw = Qfw + (size_t)128 * QK_BH;
    bf16* Vfw = Kfw + (size_t)128 * QK_BH;
    bf16* Wfw = Vfw + (size_t)128 * V_BH;          // + 384 KiB fragment-order W

    cvt_w<<<dim3(32, 3), 256, 0, stream>>>(Wq, Wk, Wv, Wfw);
    qkv_proj<<<dim3(2048), 256, 0, stream>>>(x, Wfw, bq, bk, bv, Qfw, Kfw, Vfw);
    attn<<<dim3(512), 256, 0, stream>>>(Qfw, Kfw, Vfw, outp);
}

// Round 12
// 140.405 us; speedup vs baseline: 1.1884x; 1.0049x over previous
//
#include <hip/hip_runtime.h>
#include <hip/hip_bf16.h>

#define B_   8
#define S_   1024
#define HID_ 1024
#define H_   16
#define D_   64

typedef __hip_bfloat16 bf16;
typedef __attribute__((ext_vector_type(8))) short s16x8;   // MFMA A/B frag (8 bf16)
typedef __attribute__((ext_vector_type(4))) float f32x4;   // MFMA C/D frag

// Fragment-order workspace layouts (indices in bf16 elements):
//  Qf/Kf: per bh (128 KiB): 64 row-tiles of 16 rows; per tile 1024 elems =
//         [half(2)][lane(64)][8]; lane (quad,c) holds row c, features
//         half*32+quad*8..+8  (exactly the attn A/B frag).
//  Vf:    per bh: 16 key-tiles; per tile 4096 = [et(4)][p(2)][lane(64)][8];
//         lane slot = V[key p*32+quad*4+j][feat et*16+c] (j=0..3), key+16
//         for j=4..7 — the paired-chunk PV B-frag.
//  Wf:    per (m,h): 4096 = [et(4)][half(2)][lane(64)][8].
#define QK_BH 65536
#define V_BH  65536

// f32 -> bf16 bits, round-half-up (add + shift; 2 VALU)
__device__ __forceinline__ short f2b(float f) {
    union { float f; unsigned u; } a; a.f = f;
    return (short)((a.u + 0x8000u) >> 16);
}
// load 8 consecutive f32 (32B, aligned) -> bf16 half-fragment
__device__ __forceinline__ s16x8 cvt8(const float* p) {
    const float4* q = (const float4*)p;
    float4 u = q[0], v = q[1];
    s16x8 r;
    r[0] = f2b(u.x); r[1] = f2b(u.y); r[2] = f2b(u.z); r[3] = f2b(u.w);
    r[4] = f2b(v.x); r[5] = f2b(v.y); r[6] = f2b(v.z); r[7] = f2b(v.w);
    return r;
}
__device__ __forceinline__ s16x8 load8bf(const bf16* p) {
    return *(const s16x8*)p;   // 16B load; callers guarantee alignment
}

// packed f32x2 -> bf16x2 (1 VALU for 2 elems, writes the packed dword)
__device__ __forceinline__ unsigned cvtpk_bf16(float lo, float hi) {
    unsigned r;
    asm("v_cvt_pk_bf16_f32 %0, %1, %2" : "=v"(r) : "v"(lo), "v"(hi));
    return r;
}

// async global->LDS, 16B per lane; LDS dest = wave-uniform base + lane*16
typedef __attribute__((address_space(1))) const void gvoid_t;
typedef __attribute__((address_space(3))) void lvoid_t;
__device__ __forceinline__ void gload_lds16(const bf16* g, bf16* l) {
    __builtin_amdgcn_global_load_lds((gvoid_t*)g, (lvoid_t*)l, 16, 0, 0);
}

// ---------------------------------------------------------------------------
// Kernel 0: one-shot W f32 -> bf16 in FRAGMENT ORDER.
// ---------------------------------------------------------------------------
__global__ __launch_bounds__(256) void cvt_w(
    const float* __restrict__ Wq, const float* __restrict__ Wk,
    const float* __restrict__ Wv, bf16* __restrict__ Wf)
{
    const float* srcs[3] = {Wq, Wk, Wv};
    const float* src = srcs[blockIdx.y];
    bf16* dst = Wf + (size_t)blockIdx.y * (H_ * D_ * D_);
    const int i = blockIdx.x * 256 + threadIdx.x;   // 0..8191
    const int h = i >> 9;            // 512 threads per head
    const int r = i & 511;
    const int et = r >> 7, half = (r >> 6) & 1, lane = r & 63;
    const int quad = lane >> 4, c = lane & 15;
    const float* s = src + h * 4096 + (et * 16 + c) * 64 + half * 32 + quad * 8;
    bf16* d = dst + h * 4096 + et * 1024 + half * 512 + lane * 8;
    *(s16x8*)d = cvt8(s);
}

// ---------------------------------------------------------------------------
// Kernel 1: QKV projection, FRAGMENT-ORDER outputs.  v12: 128-ROW BLOCKS
// with W-fragment REUSE.  qkv_proj is bounded in (13 µs roofline, 46 µs)
// and at full occupancy — if it's slow it's issue/latency-bound: the old
// inner loop used each L2 W-fragment load for only 2 MFMAs.  Now each
// block covers TWO 64-row chunks (rc=0,1) of the same head: per (m,et)
// the W pair is loaded ONCE and feeds 4 MFMAs (2 chunks x 2), halving
// W-load instructions per output and doubling per-wave ILP (independent
// chains per rc).  grid 1024 (bh = id&127, scp = id>>7 over 8 pairs),
// block 256, LDS 18 KB.  Wave-local math only; per-chunk code identical.
// ---------------------------------------------------------------------------
__global__ __launch_bounds__(256) void qkv_proj(
    const float* __restrict__ x, const bf16* __restrict__ Wf,
    const float* __restrict__ bq, const float* __restrict__ bk,
    const float* __restrict__ bv,
    bf16* __restrict__ Qf, bf16* __restrict__ Kf, bf16* __restrict__ Vf)
{
    __shared__ __align__(16) bf16 xs[128][72];  // 18 KiB, stride-72 padding

    const int id = blockIdx.x;
    const int bh_i = id & 127, scp = id >> 7;   // scp: 128-row pair 0..7
    const int b = bh_i >> 4, h = bh_i & 15;
    const int t = threadIdx.x;
    const int wave = t >> 6, lane = t & 63;
    const int quad = lane >> 4, c = lane & 15;
    const size_t bh = (size_t)bh_i;

    // ---- stage x[rows scp*128..+128)[h*64..+64) -> bf16 LDS, coalesced --
    {
        const float* xg = x + ((size_t)b * S_ + scp * 128) * HID_ + h * D_;
#pragma unroll
        for (int i = 0; i < 8; ++i) {
            const int j = i * 256 + t;          // 2048 float4 segments
            const int row = j >> 4, seg = j & 15;
            float4 v = *(const float4*)(xg + (size_t)row * HID_ + seg * 4);
            short4 pk;
            pk.x = f2b(v.x); pk.y = f2b(v.y); pk.z = f2b(v.z); pk.w = f2b(v.w);
            *(short4*)&xs[row][seg * 4] = pk;
        }
    }
    __syncthreads();

    // X frags for this wave's row-tile in each 64-row chunk rc:
    // local row = rc*64 + wave*16 + c
    s16x8 xa[2][2];
#pragma unroll
    for (int rc = 0; rc < 2; ++rc) {
        xa[rc][0] = *(const s16x8*)&xs[rc * 64 + wave * 16 + c][quad * 8];
        xa[rc][1] = *(const s16x8*)&xs[rc * 64 + wave * 16 + c][32 + quad * 8];
    }

    const float* bs[3] = {bq, bk, bv};

#pragma unroll 1
    for (int m = 0; m < 3; ++m) {
        const bf16*  Wm   = Wf + ((size_t)m * H_ + h) * 4096;
        const float* bias = bs[m] + h * D_;
#pragma unroll
        for (int et = 0; et < 4; ++et) {
            s16x8 wf0 = load8bf(Wm + et * 1024 + lane * 8);         // half 0
            s16x8 wf1 = load8bf(Wm + et * 1024 + 512 + lane * 8);   // half 1
            if (m < 2) {
                // D[e][s] = W·X^T : lane holds feats f = et*16+quad*4+r of
                // row (sc*4+wave)*16 + c, sc = scp*2+rc.
                const int hp = et >> 1;
                const int qp = (2 * et + (quad >> 1)) & 3;
                const float4 bb = *(const float4*)&bias[et * 16 + quad * 4];
#pragma unroll
                for (int rc = 0; rc < 2; ++rc) {
                    f32x4 acc = {0.f, 0.f, 0.f, 0.f};
                    acc = __builtin_amdgcn_mfma_f32_16x16x32_bf16(wf0, xa[rc][0], acc, 0, 0, 0);
                    acc = __builtin_amdgcn_mfma_f32_16x16x32_bf16(wf1, xa[rc][1], acc, 0, 0, 0);
                    const int ts = (scp * 2 + rc) * 4 + wave;   // row-tile
                    bf16* dst = (m == 0 ? Qf : Kf) + bh * QK_BH + ts * 1024 +
                                hp * 512 + (qp * 16 + c) * 8 + (quad & 1) * 4;
                    short4 pk;
                    pk.x = f2b(acc[0] + bb.x);
                    pk.y = f2b(acc[1] + bb.y);
                    pk.z = f2b(acc[2] + bb.z);
                    pk.w = f2b(acc[3] + bb.w);
                    *(short4*)dst = pk;
                }
            } else {
                // D[s][e] = X·W^T : lane holds keys wave*16+quad*4+r of
                // feature et*16+c.  Key-tile = sc = scp*2+rc.
                const float bbv = bias[et * 16 + c];
#pragma unroll
                for (int rc = 0; rc < 2; ++rc) {
                    f32x4 acc = {0.f, 0.f, 0.f, 0.f};
                    acc = __builtin_amdgcn_mfma_f32_16x16x32_bf16(xa[rc][0], wf0, acc, 0, 0, 0);
                    acc = __builtin_amdgcn_mfma_f32_16x16x32_bf16(xa[rc][1], wf1, acc, 0, 0, 0);
                    bf16* dst = Vf + bh * V_BH + (scp * 2 + rc) * 4096 + et * 1024 +
                                (wave >> 1) * 512 + (quad * 16 + c) * 8 + (wave & 1) * 4;
                    short4 pk;
                    pk.x = f2b(acc[0] + bbv);
                    pk.y = f2b(acc[1] + bbv);
                    pk.z = f2b(acc[2] + bbv);
                    pk.w = f2b(acc[3] + bbv);
                    *(short4*)dst = pk;
                }
            }
        }
    }
}

// ---------------------------------------------------------------------------
// Kernel 2: MFMA flash attention — the PROVEN v2/v6 form, byte-identical
// to R1 (grid 512, 4 row-tiles/wave, 2 blocks/CU, global_load_lds dbuf in
// its only verified shape).  Occupancy arc closed after 6 attempts: every
// restructuring around global_load_lds corrupts (v3,v4,v5,v8,v10); the
// alternatives that pass (reg-staged v9, unstaged v7) are slower.
// ---------------------------------------------------------------------------
__global__ __launch_bounds__(256, 2) void attn(
    const bf16* __restrict__ Qf, const bf16* __restrict__ Kf,
    const bf16* __restrict__ Vf, float* __restrict__ out)
{
    __shared__ __align__(16) union {
        bf16  kv[2][8192];        // [buf][ K: 4096 elems | V: 4096 elems ]
        float os[4][16][68];      // epilogue staging (after last barrier)
    } sm;

    const int id = blockIdx.x;
    const int bh_i = id & 127, qc = id >> 7;        // qc 0..3, 256 rows each
    const int b = bh_i >> 4, h = bh_i & 15;
    const int wave = threadIdx.x >> 6, lane = threadIdx.x & 63;
    const int quad = lane >> 4, c = lane & 15;
    const int ts0 = qc * 16 + wave * 4;             // first of 4 row-tiles
    const size_t bh = (size_t)bh_i;

    // Q fragments for 4 row-tiles (B-operand of swapped QK)
    s16x8 aq[4][2];
#pragma unroll
    for (int mt = 0; mt < 4; ++mt) {
        const bf16* Qb = Qf + bh * QK_BH + (ts0 + mt) * 1024 + lane * 8;
        aq[mt][0] = load8bf(Qb);
        aq[mt][1] = load8bf(Qb + 512);
    }

    const f32x4 zero4 = {0.f, 0.f, 0.f, 0.f};
    f32x4 o[4][4];
    f32x4 ld4[4];                 // denominator accumulators (ones-MFMA)
#pragma unroll
    for (int mt = 0; mt < 4; ++mt) {
        ld4[mt] = zero4;
#pragma unroll
        for (int et = 0; et < 4; ++et) o[mt][et] = zero4;
    }

    s16x8 ones;                   // bf16 1.0 B-fragment
#pragma unroll
    for (int j = 0; j < 8; ++j) ones[j] = (short)0x3F80;

    const float CEXP = 0.18033688011112042f;           // (1/sqrt(64))*log2(e)
    const float NM0  = -16.0f * 0.18033688011112042f;  // fixed shift m0=16

    const bf16* Kg = Kf + bh * QK_BH;   // + kt*4096 elems per k-tile (8 KB)
    const bf16* Vg = Vf + bh * V_BH;    // + kt*4096 elems per k-tile (8 KB)

    // stage one 16 KB k-tile (K 8 KB | V 8 KB) into LDS buffer bi.
    // 16 chunks of 1 KB; wave w issues chunks w*4..w*4+3 (waves 0,1 -> K,
    // waves 2,3 -> V).  LDS dest linear: uniform base + lane*16B.
    auto STAGE = [&](int kt, int bi) {
#pragma unroll
        for (int i = 0; i < 4; ++i) {
            const int ch = wave * 4 + i;                      // 0..15
            const bf16* src = (ch < 8
                ? Kg + (size_t)kt * 4096 + ch * 512
                : Vg + (size_t)kt * 4096 + (ch - 8) * 512) + lane * 8;
            gload_lds16(src, &sm.kv[bi][ch * 512]);
        }
    };

    STAGE(0, 0);
    __syncthreads();              // drains vmcnt -> buf0 ready

    int cur = 0;
#pragma unroll 1
    for (int kt = 0; kt < S_ / 64; ++kt) {
        // prefetch next tile into the other buffer (drained at this
        // iteration's end-of-loop barrier -> hidden under compute below)
        if (kt < S_ / 64 - 1) STAGE(kt + 1, cur ^ 1);

        const bf16* kb = &sm.kv[cur][0];
        const bf16* vb = &sm.kv[cur][4096];

        // ---- tile fragments from LDS (16 linear ds_read_b128 / lane) ----
        s16x8 ka[4], kb2[4];
#pragma unroll
        for (int ct = 0; ct < 4; ++ct) {
            ka[ct]  = load8bf(kb + ct * 1024 + lane * 8);
            kb2[ct] = load8bf(kb + ct * 1024 + 512 + lane * 8);
        }
        s16x8 vf4[4][2];
#pragma unroll
        for (int et = 0; et < 4; ++et)
#pragma unroll
            for (int p = 0; p < 2; ++p)
                vf4[et][p] = load8bf(vb + et * 1024 + p * 512 + lane * 8);

        // ---- per row-tile: QK^T -> softmax -> PV (P stays in registers) --
#pragma unroll
        for (int mt = 0; mt < 4; ++mt) {
            f32x4 s4[4];
#pragma unroll
            for (int ct = 0; ct < 4; ++ct) {
                f32x4 acc = zero4;
                acc = __builtin_amdgcn_mfma_f32_16x16x32_bf16(ka[ct],  aq[mt][0], acc, 0, 0, 0);
                acc = __builtin_amdgcn_mfma_f32_16x16x32_bf16(kb2[ct], aq[mt][1], acc, 0, 0, 0);
                s4[ct] = acc;
            }
            s16x8 pz[2];
#pragma unroll
            for (int p = 0; p < 2; ++p) {
                float pa[4], pb[4];
#pragma unroll
                for (int j = 0; j < 4; ++j) {
                    pa[j] = __builtin_amdgcn_exp2f(fmaf(s4[2 * p][j],     CEXP, NM0));
                    pb[j] = __builtin_amdgcn_exp2f(fmaf(s4[2 * p + 1][j], CEXP, NM0));
                }
                union { unsigned u[4]; s16x8 v; } z;
                z.u[0] = cvtpk_bf16(pa[0], pa[1]);
                z.u[1] = cvtpk_bf16(pa[2], pa[3]);
                z.u[2] = cvtpk_bf16(pb[0], pb[1]);
                z.u[3] = cvtpk_bf16(pb[2], pb[3]);
                pz[p] = z.v;
            }
            // denominator: row-sum of bf16 P via ones-column MFMA
            ld4[mt] = __builtin_amdgcn_mfma_f32_16x16x32_bf16(pz[0], ones, ld4[mt], 0, 0, 0);
            ld4[mt] = __builtin_amdgcn_mfma_f32_16x16x32_bf16(pz[1], ones, ld4[mt], 0, 0, 0);
#pragma unroll
            for (int et = 0; et < 4; ++et) {
                o[mt][et] = __builtin_amdgcn_mfma_f32_16x16x32_bf16(pz[0], vf4[et][0], o[mt][et], 0, 0, 0);
                o[mt][et] = __builtin_amdgcn_mfma_f32_16x16x32_bf16(pz[1], vf4[et][1], o[mt][et], 0, 0, 0);
            }
        }
        __syncthreads();          // all waves done with kv[cur]; prefetch
        cur ^= 1;                 // into kv[cur^1] drained (vmcnt 0)
    }

    // ---- epilogue per row-tile: ld4[mt][r] already holds the full row
    //      denom (replicated across the 16 lanes of the row group -> no
    //      shuffles), normalize, LDS transpose, contiguous float4 stores.
    //      sm.kv is dead after the final barrier above; os aliases it. ----
#pragma unroll
    for (int mt = 0; mt < 4; ++mt) {
        float inv[4];
#pragma unroll
        for (int r = 0; r < 4; ++r) inv[r] = 1.0f / ld4[mt][r];
#pragma unroll
        for (int et = 0; et < 4; ++et)
#pragma unroll
            for (int r = 0; r < 4; ++r)
                sm.os[wave][quad * 4 + r][et * 16 + c] = o[mt][et][r] * inv[r];
        float* orow = out + ((size_t)b * S_ + (ts0 + mt) * 16 + c) * HID_ + h * D_;
#pragma unroll
        for (int j = 0; j < 4; ++j) {
            float4 v = *(const float4*)&sm.os[wave][c][(quad + j * 4) * 4];
            *(float4*)(orow + (quad + j * 4) * 4) = v;
        }
    }
}

// ---------------------------------------------------------------------------
extern "C" void kernel_launch(void* const* d_in, const int* in_sizes, int n_in,
                              void* d_out, int out_size, void* d_ws, size_t ws_size,
                              hipStream_t stream) {
    (void)in_sizes; (void)n_in; (void)out_size; (void)ws_size;
    const float* x  = (const float*)d_in[0];
    const float* Wq = (const float*)d_in[1];
    const float* bq = (const float*)d_in[2];
    const float* Wk = (const float*)d_in[3];
    const float* bk = (const float*)d_in[4];
    const float* Wv = (const float*)d_in[5];
    const float* bv = (const float*)d_in[6];
    float* outp = (float*)d_out;   // reference output dtype is float32

    bf16* Qfw = (bf16*)d_ws;                       // 128 bh * 64K elems
    bf16* Kfw = Qfw + (size_t)128 * QK_BH;
    bf16* Vfw = Kfw + (size_t)128 * QK_BH;
    bf16* Wfw = Vfw + (size_t)128 * V_BH;          // + 384 KiB fragment-order W

    cvt_w<<<dim3(32, 3), 256, 0, stream>>>(Wq, Wk, Wv, Wfw);
    qkv_proj<<<dim3(1024), 256, 0, stream>>>(x, Wfw, bq, bk, bv, Qfw, Kfw, Vfw);
    attn<<<dim3(512), 256, 0, stream>>>(Qfw, Kfw, Vfw, outp);
}

// Round 14
// 139.870 us; speedup vs baseline: 1.1929x; 1.0038x over previous
//
#include <hip/hip_runtime.h>
#include <hip/hip_bf16.h>

#define B_   8
#define S_   1024
#define HID_ 1024
#define H_   16
#define D_   64

typedef __hip_bfloat16 bf16;
typedef __attribute__((ext_vector_type(8))) short s16x8;   // MFMA A/B frag (8 bf16)
typedef __attribute__((ext_vector_type(4))) float f32x4;   // MFMA C/D frag

// Fragment-order workspace layouts (indices in bf16 elements):
//  Qf/Kf: per bh (128 KiB): 64 row-tiles of 16 rows; per tile 1024 elems =
//         [half(2)][lane(64)][8]; lane (quad,c) holds row c, features
//         half*32+quad*8..+8  (exactly the attn A/B frag).
//  Vf:    per bh: 16 key-tiles; per tile 4096 = [et(4)][p(2)][lane(64)][8];
//         lane slot = V[key p*32+quad*4+j][feat et*16+c] (j=0..3), key+16
//         for j=4..7 — the paired-chunk PV B-frag.
//  Wf:    per (m,h): 4096 = [et(4)][half(2)][lane(64)][8].
//  NOTE (R14): Qf stores Q PRE-SCALED by CEXP = (1/sqrt(64))*log2(e), so
//  attn computes P = exp2(QK') directly (no fmaf, no shift constant —
//  the old fixed shift 2^NM0 cancels exactly in o/l).
#define QK_BH 65536
#define V_BH  65536

// f32 -> bf16 bits, round-half-up (add + shift; 2 VALU)
__device__ __forceinline__ short f2b(float f) {
    union { float f; unsigned u; } a; a.f = f;
    return (short)((a.u + 0x8000u) >> 16);
}
// load 8 consecutive f32 (32B, aligned) -> bf16 half-fragment
__device__ __forceinline__ s16x8 cvt8(const float* p) {
    const float4* q = (const float4*)p;
    float4 u = q[0], v = q[1];
    s16x8 r;
    r[0] = f2b(u.x); r[1] = f2b(u.y); r[2] = f2b(u.z); r[3] = f2b(u.w);
    r[4] = f2b(v.x); r[5] = f2b(v.y); r[6] = f2b(v.z); r[7] = f2b(v.w);
    return r;
}
__device__ __forceinline__ s16x8 load8bf(const bf16* p) {
    return *(const s16x8*)p;   // 16B load; callers guarantee alignment
}

// packed f32x2 -> bf16x2 (1 VALU for 2 elems, writes the packed dword)
__device__ __forceinline__ unsigned cvtpk_bf16(float lo, float hi) {
    unsigned r;
    asm("v_cvt_pk_bf16_f32 %0, %1, %2" : "=v"(r) : "v"(lo), "v"(hi));
    return r;
}

// async global->LDS, 16B per lane; LDS dest = wave-uniform base + lane*16
typedef __attribute__((address_space(1))) const void gvoid_t;
typedef __attribute__((address_space(3))) void lvoid_t;
__device__ __forceinline__ void gload_lds16(const bf16* g, bf16* l) {
    __builtin_amdgcn_global_load_lds((gvoid_t*)g, (lvoid_t*)l, 16, 0, 0);
}

// ---------------------------------------------------------------------------
// Kernel 0: one-shot W f32 -> bf16 in FRAGMENT ORDER.
// ---------------------------------------------------------------------------
__global__ __launch_bounds__(256) void cvt_w(
    const float* __restrict__ Wq, const float* __restrict__ Wk,
    const float* __restrict__ Wv, bf16* __restrict__ Wf)
{
    const float* srcs[3] = {Wq, Wk, Wv};
    const float* src = srcs[blockIdx.y];
    bf16* dst = Wf + (size_t)blockIdx.y * (H_ * D_ * D_);
    const int i = blockIdx.x * 256 + threadIdx.x;   // 0..8191
    const int h = i >> 9;            // 512 threads per head
    const int r = i & 511;
    const int et = r >> 7, half = (r >> 6) & 1, lane = r & 63;
    const int quad = lane >> 4, c = lane & 15;
    const float* s = src + h * 4096 + (et * 16 + c) * 64 + half * 32 + quad * 8;
    bf16* d = dst + h * 4096 + et * 1024 + half * 512 + lane * 8;
    *(s16x8*)d = cvt8(s);
}

// ---------------------------------------------------------------------------
// Kernel 1: QKV projection, FRAGMENT-ORDER outputs.  128-row blocks with
// W-fragment reuse (R12 form, passed).  R14: the Q output (m==0) is
// multiplied by CEXP after the bias add — moving the softmax scale OFF
// attn's critical dependency chain (one extra VALU mul here, fully
// hidden; deletes 64 fmaf per wave-k-tile in attn).
// grid 1024 (bh = id&127, scp = id>>7), block 256, LDS 18 KB.
// ---------------------------------------------------------------------------
__global__ __launch_bounds__(256) void qkv_proj(
    const float* __restrict__ x, const bf16* __restrict__ Wf,
    const float* __restrict__ bq, const float* __restrict__ bk,
    const float* __restrict__ bv,
    bf16* __restrict__ Qf, bf16* __restrict__ Kf, bf16* __restrict__ Vf)
{
    __shared__ __align__(16) bf16 xs[128][72];  // 18 KiB, stride-72 padding

    const int id = blockIdx.x;
    const int bh_i = id & 127, scp = id >> 7;   // scp: 128-row pair 0..7
    const int b = bh_i >> 4, h = bh_i & 15;
    const int t = threadIdx.x;
    const int wave = t >> 6, lane = t & 63;
    const int quad = lane >> 4, c = lane & 15;
    const size_t bh = (size_t)bh_i;
    const float CEXP = 0.18033688011112042f;    // (1/sqrt(64))*log2(e)

    // ---- stage x[rows scp*128..+128)[h*64..+64) -> bf16 LDS, coalesced --
    {
        const float* xg = x + ((size_t)b * S_ + scp * 128) * HID_ + h * D_;
#pragma unroll
        for (int i = 0; i < 8; ++i) {
            const int j = i * 256 + t;          // 2048 float4 segments
            const int row = j >> 4, seg = j & 15;
            float4 v = *(const float4*)(xg + (size_t)row * HID_ + seg * 4);
            short4 pk;
            pk.x = f2b(v.x); pk.y = f2b(v.y); pk.z = f2b(v.z); pk.w = f2b(v.w);
            *(short4*)&xs[row][seg * 4] = pk;
        }
    }
    __syncthreads();

    // X frags for this wave's row-tile in each 64-row chunk rc:
    // local row = rc*64 + wave*16 + c
    s16x8 xa[2][2];
#pragma unroll
    for (int rc = 0; rc < 2; ++rc) {
        xa[rc][0] = *(const s16x8*)&xs[rc * 64 + wave * 16 + c][quad * 8];
        xa[rc][1] = *(const s16x8*)&xs[rc * 64 + wave * 16 + c][32 + quad * 8];
    }

    const float* bs[3] = {bq, bk, bv};

#pragma unroll 1
    for (int m = 0; m < 3; ++m) {
        const bf16*  Wm   = Wf + ((size_t)m * H_ + h) * 4096;
        const float* bias = bs[m] + h * D_;
#pragma unroll
        for (int et = 0; et < 4; ++et) {
            s16x8 wf0 = load8bf(Wm + et * 1024 + lane * 8);         // half 0
            s16x8 wf1 = load8bf(Wm + et * 1024 + 512 + lane * 8);   // half 1
            if (m < 2) {
                // D[e][s] = W·X^T : lane holds feats f = et*16+quad*4+r of
                // row (sc*4+wave)*16 + c, sc = scp*2+rc.
                const int hp = et >> 1;
                const int qp = (2 * et + (quad >> 1)) & 3;
                const float4 bb = *(const float4*)&bias[et * 16 + quad * 4];
                const float sc_m = (m == 0) ? CEXP : 1.0f;  // Q pre-scale
#pragma unroll
                for (int rc = 0; rc < 2; ++rc) {
                    f32x4 acc = {0.f, 0.f, 0.f, 0.f};
                    acc = __builtin_amdgcn_mfma_f32_16x16x32_bf16(wf0, xa[rc][0], acc, 0, 0, 0);
                    acc = __builtin_amdgcn_mfma_f32_16x16x32_bf16(wf1, xa[rc][1], acc, 0, 0, 0);
                    const int ts = (scp * 2 + rc) * 4 + wave;   // row-tile
                    bf16* dst = (m == 0 ? Qf : Kf) + bh * QK_BH + ts * 1024 +
                                hp * 512 + (qp * 16 + c) * 8 + (quad & 1) * 4;
                    short4 pk;
                    pk.x = f2b((acc[0] + bb.x) * sc_m);
                    pk.y = f2b((acc[1] + bb.y) * sc_m);
                    pk.z = f2b((acc[2] + bb.z) * sc_m);
                    pk.w = f2b((acc[3] + bb.w) * sc_m);
                    *(short4*)dst = pk;
                }
            } else {
                // D[s][e] = X·W^T : lane holds keys wave*16+quad*4+r of
                // feature et*16+c.  Key-tile = sc = scp*2+rc.
                const float bbv = bias[et * 16 + c];
#pragma unroll
                for (int rc = 0; rc < 2; ++rc) {
                    f32x4 acc = {0.f, 0.f, 0.f, 0.f};
                    acc = __builtin_amdgcn_mfma_f32_16x16x32_bf16(xa[rc][0], wf0, acc, 0, 0, 0);
                    acc = __builtin_amdgcn_mfma_f32_16x16x32_bf16(xa[rc][1], wf1, acc, 0, 0, 0);
                    bf16* dst = Vf + bh * V_BH + (scp * 2 + rc) * 4096 + et * 1024 +
                                (wave >> 1) * 512 + (quad * 16 + c) * 8 + (wave & 1) * 4;
                    short4 pk;
                    pk.x = f2b(acc[0] + bbv);
                    pk.y = f2b(acc[1] + bbv);
                    pk.z = f2b(acc[2] + bbv);
                    pk.w = f2b(acc[3] + bbv);
                    *(short4*)dst = pk;
                }
            }
        }
    }
}

// ---------------------------------------------------------------------------
// Kernel 2: MFMA flash attention — the PROVEN v2/v6 STRUCTURE, frozen
// (grid 512, 4 row-tiles/wave, 2 blocks/CU, global_load_lds dbuf in its
// only verified shape; 8 restructures / 6 correctness failures closed the
// arc).  R14 delta is REGISTER-ONLY inside the softmax: Q arrives
// pre-scaled by CEXP, and the fixed shift 2^NM0 cancels in o/l — so
// P = exp2(s4) directly.  Deletes 16 fmaf per row-tile (64 VALU per
// wave-k-tile) from the QK->exp->PV critical chain.  P is now bounded by
// ~2^8 instead of 1 (f32/bf16-safe; same relative precision).
// ---------------------------------------------------------------------------
__global__ __launch_bounds__(256, 2) void attn(
    const bf16* __restrict__ Qf, const bf16* __restrict__ Kf,
    const bf16* __restrict__ Vf, float* __restrict__ out)
{
    __shared__ __align__(16) union {
        bf16  kv[2][8192];        // [buf][ K: 4096 elems | V: 4096 elems ]
        float os[4][16][68];      // epilogue staging (after last barrier)
    } sm;

    const int id = blockIdx.x;
    const int bh_i = id & 127, qc = id >> 7;        // qc 0..3, 256 rows each
    const int b = bh_i >> 4, h = bh_i & 15;
    const int wave = threadIdx.x >> 6, lane = threadIdx.x & 63;
    const int quad = lane >> 4, c = lane & 15;
    const int ts0 = qc * 16 + wave * 4;             // first of 4 row-tiles
    const size_t bh = (size_t)bh_i;

    // Q fragments for 4 row-tiles (B-operand of swapped QK)
    s16x8 aq[4][2];
#pragma unroll
    for (int mt = 0; mt < 4; ++mt) {
        const bf16* Qb = Qf + bh * QK_BH + (ts0 + mt) * 1024 + lane * 8;
        aq[mt][0] = load8bf(Qb);
        aq[mt][1] = load8bf(Qb + 512);
    }

    const f32x4 zero4 = {0.f, 0.f, 0.f, 0.f};
    f32x4 o[4][4];
    f32x4 ld4[4];                 // denominator accumulators (ones-MFMA)
#pragma unroll
    for (int mt = 0; mt < 4; ++mt) {
        ld4[mt] = zero4;
#pragma unroll
        for (int et = 0; et < 4; ++et) o[mt][et] = zero4;
    }

    s16x8 ones;                   // bf16 1.0 B-fragment
#pragma unroll
    for (int j = 0; j < 8; ++j) ones[j] = (short)0x3F80;

    const bf16* Kg = Kf + bh * QK_BH;   // + kt*4096 elems per k-tile (8 KB)
    const bf16* Vg = Vf + bh * V_BH;    // + kt*4096 elems per k-tile (8 KB)

    // stage one 16 KB k-tile (K 8 KB | V 8 KB) into LDS buffer bi.
    // 16 chunks of 1 KB; wave w issues chunks w*4..w*4+3 (waves 0,1 -> K,
    // waves 2,3 -> V).  LDS dest linear: uniform base + lane*16B.
    auto STAGE = [&](int kt, int bi) {
#pragma unroll
        for (int i = 0; i < 4; ++i) {
            const int ch = wave * 4 + i;                      // 0..15
            const bf16* src = (ch < 8
                ? Kg + (size_t)kt * 4096 + ch * 512
                : Vg + (size_t)kt * 4096 + (ch - 8) * 512) + lane * 8;
            gload_lds16(src, &sm.kv[bi][ch * 512]);
        }
    };

    STAGE(0, 0);
    __syncthreads();              // drains vmcnt -> buf0 ready

    int cur = 0;
#pragma unroll 1
    for (int kt = 0; kt < S_ / 64; ++kt) {
        // prefetch next tile into the other buffer (drained at this
        // iteration's end-of-loop barrier -> hidden under compute below)
        if (kt < S_ / 64 - 1) STAGE(kt + 1, cur ^ 1);

        const bf16* kb = &sm.kv[cur][0];
        const bf16* vb = &sm.kv[cur][4096];

        // ---- tile fragments from LDS (16 linear ds_read_b128 / lane) ----
        s16x8 ka[4], kb2[4];
#pragma unroll
        for (int ct = 0; ct < 4; ++ct) {
            ka[ct]  = load8bf(kb + ct * 1024 + lane * 8);
            kb2[ct] = load8bf(kb + ct * 1024 + 512 + lane * 8);
        }
        s16x8 vf4[4][2];
#pragma unroll
        for (int et = 0; et < 4; ++et)
#pragma unroll
            for (int p = 0; p < 2; ++p)
                vf4[et][p] = load8bf(vb + et * 1024 + p * 512 + lane * 8);

        // ---- per row-tile: QK^T -> softmax -> PV (P stays in registers) --
#pragma unroll
        for (int mt = 0; mt < 4; ++mt) {
            f32x4 s4[4];
#pragma unroll
            for (int ct = 0; ct < 4; ++ct) {
                f32x4 acc = zero4;
                acc = __builtin_amdgcn_mfma_f32_16x16x32_bf16(ka[ct],  aq[mt][0], acc, 0, 0, 0);
                acc = __builtin_amdgcn_mfma_f32_16x16x32_bf16(kb2[ct], aq[mt][1], acc, 0, 0, 0);
                s4[ct] = acc;
            }
            s16x8 pz[2];
#pragma unroll
            for (int p = 0; p < 2; ++p) {
                float pa[4], pb[4];
#pragma unroll
                for (int j = 0; j < 4; ++j) {
                    pa[j] = __builtin_amdgcn_exp2f(s4[2 * p][j]);
                    pb[j] = __builtin_amdgcn_exp2f(s4[2 * p + 1][j]);
                }
                union { unsigned u[4]; s16x8 v; } z;
                z.u[0] = cvtpk_bf16(pa[0], pa[1]);
                z.u[1] = cvtpk_bf16(pa[2], pa[3]);
                z.u[2] = cvtpk_bf16(pb[0], pb[1]);
                z.u[3] = cvtpk_bf16(pb[2], pb[3]);
                pz[p] = z.v;
            }
            // denominator: row-sum of bf16 P via ones-column MFMA
            ld4[mt] = __builtin_amdgcn_mfma_f32_16x16x32_bf16(pz[0], ones, ld4[mt], 0, 0, 0);
            ld4[mt] = __builtin_amdgcn_mfma_f32_16x16x32_bf16(pz[1], ones, ld4[mt], 0, 0, 0);
#pragma unroll
            for (int et = 0; et < 4; ++et) {
                o[mt][et] = __builtin_amdgcn_mfma_f32_16x16x32_bf16(pz[0], vf4[et][0], o[mt][et], 0, 0, 0);
                o[mt][et] = __builtin_amdgcn_mfma_f32_16x16x32_bf16(pz[1], vf4[et][1], o[mt][et], 0, 0, 0);
            }
        }
        __syncthreads();          // all waves done with kv[cur]; prefetch
        cur ^= 1;                 // into kv[cur^1] drained (vmcnt 0)
    }

    // ---- epilogue per row-tile: ld4[mt][r] already holds the full row
    //      denom (replicated across the 16 lanes of the row group -> no
    //      shuffles), normalize, LDS transpose, contiguous float4 stores.
    //      sm.kv is dead after the final barrier above; os aliases it. ----
#pragma unroll
    for (int mt = 0; mt < 4; ++mt) {
        float inv[4];
#pragma unroll
        for (int r = 0; r < 4; ++r) inv[r] = 1.0f / ld4[mt][r];
#pragma unroll
        for (int et = 0; et < 4; ++et)
#pragma unroll
            for (int r = 0; r < 4; ++r)
                sm.os[wave][quad * 4 + r][et * 16 + c] = o[mt][et][r] * inv[r];
        float* orow = out + ((size_t)b * S_ + (ts0 + mt) * 16 + c) * HID_ + h * D_;
#pragma unroll
        for (int j = 0; j < 4; ++j) {
            float4 v = *(const float4*)&sm.os[wave][c][(quad + j * 4) * 4];
            *(float4*)(orow + (quad + j * 4) * 4) = v;
        }
    }
}

// ---------------------------------------------------------------------------
extern "C" void kernel_launch(void* const* d_in, const int* in_sizes, int n_in,
                              void* d_out, int out_size, void* d_ws, size_t ws_size,
                              hipStream_t stream) {
    (void)in_sizes; (void)n_in; (void)out_size; (void)ws_size;
    const float* x  = (const float*)d_in[0];
    const float* Wq = (const float*)d_in[1];
    const float* bq = (const float*)d_in[2];
    const float* Wk = (const float*)d_in[3];
    const float* bk = (const float*)d_in[4];
    const float* Wv = (const float*)d_in[5];
    const float* bv = (const float*)d_in[6];
    float* outp = (float*)d_out;   // reference output dtype is float32

    bf16* Qfw = (bf16*)d_ws;                       // 128 bh * 64K elems
    bf16* Kfw = Qfw + (size_t)128 * QK_BH;
    bf16* Vfw = Kfw + (size_t)128 * QK_BH;
    bf16* Wfw = Vfw + (size_t)128 * V_BH;          // + 384 KiB fragment-order W

    cvt_w<<<dim3(32, 3), 256, 0, stream>>>(Wq, Wk, Wv, Wfw);
    qkv_proj<<<dim3(1024), 256, 0, stream>>>(x, Wfw, bq, bk, bv, Qfw, Kfw, Vfw);
    attn<<<dim3(512), 256, 0, stream>>>(Qfw, Kfw, Vfw, outp);
}